// Round 6
// baseline (299.861 us; speedup 1.0000x reference)
//
#include <hip/hip_runtime.h>

#define B_ 4
#define L_ 2048
#define D_ 1024
#define M_FLAT (B_*L_)   // 8192

typedef unsigned short bf16_t;
typedef __attribute__((ext_vector_type(8))) short bf16x8;
typedef __attribute__((ext_vector_type(4))) float f32x4;

__device__ __forceinline__ bf16_t f2bf(float f) {
  union { float f; unsigned int u; } c; c.f = f;
  unsigned int u = c.u;
  unsigned int r = (u + 0x7fffu + ((u >> 16) & 1u)) >> 16;
  return (bf16_t)r;
}
__device__ __forceinline__ float bf2f(bf16_t h) {
  union { unsigned int u; float f; } c; c.u = ((unsigned int)h) << 16;
  return c.f;
}

__device__ __forceinline__ void gload_lds16(const bf16_t* g, bf16_t* l) {
  __builtin_amdgcn_global_load_lds(
      (const __attribute__((address_space(1))) unsigned int*)g,
      (__attribute__((address_space(3))) unsigned int*)l, 16, 0, 0);
}

#define BARRIER() do { asm volatile("" ::: "memory"); \
                       __builtin_amdgcn_s_barrier();  \
                       asm volatile("" ::: "memory"); } while (0)

// ---- elementwise fp32 -> bf16 convert, 8 elts/thread ----
__global__ __launch_bounds__(256) void cvt_bf16(const float* __restrict__ in,
                                                bf16_t* __restrict__ out) {
  size_t i = (size_t)blockIdx.x * 256 + threadIdx.x;
  const float4* p = (const float4*)in + i * 2;
  float4 a = p[0], b = p[1];
  union { bf16_t h[8]; uint4 u; } r;
  r.h[0] = f2bf(a.x); r.h[1] = f2bf(a.y); r.h[2] = f2bf(a.z); r.h[3] = f2bf(a.w);
  r.h[4] = f2bf(b.x); r.h[5] = f2bf(b.y); r.h[6] = f2bf(b.z); r.h[7] = f2bf(b.w);
  ((uint4*)out)[i] = r.u;
}

// ---- 1024x1024 fp32 -> transposed bf16 (W -> W^T) ----
__global__ __launch_bounds__(256) void transpose_cvt(const float* __restrict__ Wsrc,
                                                     bf16_t* __restrict__ Wt) {
  __shared__ float t[32][33];
  int c0 = blockIdx.x * 32, r0 = blockIdx.y * 32;
  int tx = threadIdx.x, ty = threadIdx.y;   // block (32,8)
#pragma unroll
  for (int i = 0; i < 4; i++)
    t[ty + i * 8][tx] = Wsrc[(size_t)(r0 + ty + i * 8) * D_ + c0 + tx];
  __syncthreads();
#pragma unroll
  for (int i = 0; i < 4; i++)
    Wt[(size_t)(c0 + ty + i * 8) * D_ + r0 + tx] = f2bf(t[tx][ty + i * 8]);
}

// ---- generic bf16 transpose (R x C) -> (C x R), batched by z ----
__global__ __launch_bounds__(256) void transpose_bf16(const bf16_t* __restrict__ in,
                                                      bf16_t* __restrict__ out,
                                                      int R, int C, long strIn, long strOut) {
  __shared__ bf16_t t[32][33];
  int c0 = blockIdx.x * 32, r0 = blockIdx.y * 32;
  int tx = threadIdx.x, ty = threadIdx.y;   // block (32,8)
  const bf16_t* ip = in + (size_t)blockIdx.z * strIn;
  bf16_t* op = out + (size_t)blockIdx.z * strOut;
#pragma unroll
  for (int i = 0; i < 4; i++)
    t[ty + i * 8][tx] = ip[(size_t)(r0 + ty + i * 8) * C + c0 + tx];
  __syncthreads();
#pragma unroll
  for (int i = 0; i < 4; i++)
    op[(size_t)(c0 + ty + i * 8) * R + r0 + tx] = t[tx][ty + i * 8];
}

// ---- c2 = bv . Wo  (row vector, 1024) ----
__global__ __launch_bounds__(256) void c2_kernel(const float* __restrict__ bv,
                                                 const float* __restrict__ Wo,
                                                 float* __restrict__ c2) {
  int j = blockIdx.x * 256 + threadIdx.x;  // 1024
  float s = 0.f;
  for (int k = 0; k < D_; k++) s += bv[k] * Wo[(size_t)k * D_ + j];
  c2[j] = s;
}

// ---- pack int32 mask -> 1 bit/elem (64 ints -> one u64 via ballot) ----
__global__ __launch_bounds__(256) void pack_mask(const int* __restrict__ mask,
                                                 unsigned long long* __restrict__ bm) {
  size_t gid = (size_t)blockIdx.x * 256 + threadIdx.x;
  int mi = mask[gid];
  unsigned long long b = __ballot(mi != 0);
  if ((threadIdx.x & 63) == 0) bm[gid >> 6] = b;
}

// ---- reduce 32 rowsum partials -> rsum (guarded) ----
__global__ __launch_bounds__(256) void reduce_rsum(const float* __restrict__ rsp,
                                                   float* __restrict__ rs) {
  int r = blockIdx.x * 256 + threadIdx.x;   // 8192 rows
  float s = 0.f;
#pragma unroll
  for (int j = 0; j < 32; j++) s += rsp[(size_t)r * 32 + j];
  rs[r] = fmaxf(s, 1e-30f);
}

// ================= 8-phase BMx256 BK=64 GEMM =================================
// C = A(MxK) * Bt(NxK)^T.  8 waves (2M x 4N), 512 threads, 2 K-steps/iter.
// LDS swizzle: elem (r,k) at byte r*128 + ((k>>3)^(r&7))*16 + (k&7)*2.
// Panel-affine XCD mapping: hw id f0 -> (xb,yb,zb) such that all x-blocks of
// one A-panel share f0%8 (same XCD) and sweep K in lockstep -> panel re-reads
// are L2 hits instead of LLC round trips.
#define MODE_PROJ 0  // z=0: Q=(acc+bq)/32; z=1: K=acc+bk; z=2: VW=acc+c2
#define MODE_BF16 1  // plain bf16 out (raw blockIdx; small grids)
#define MODE_S    2  // P = maskbit ? exp(acc) : 0 (bf16) + partial rowsums
#define MODE_FIN  3  // fp32 out = acc/rs[r] + bias[c]

template <int BM, int MODE>
__global__ __launch_bounds__(512, 2)
void g8(const bf16_t* __restrict__ Abase, int lda, long strA,
        const bf16_t* __restrict__ Bbase, int ldb, long strB,
        void* __restrict__ outp, long strO, int ldo,
        const float* __restrict__ x0, const float* __restrict__ x1,
        const float* __restrict__ x2,
        const void* __restrict__ auxp, float* __restrict__ rsp,
        int K) {
  constexpr int WROWS = BM / 2;
  constexpr int QAF   = WROWS / 32;
  constexpr int MFR   = WROWS / 16;
  constexpr int AL    = BM / 128;
  constexpr int BL    = 2;
  constexpr int AHB   = WROWS * 128;
  constexpr int BUFB  = (BM + 256) * 128;
  extern __shared__ __align__(16) char smem[];

  const int tid = threadIdx.x, lane = tid & 63, w = tid >> 6;
  const int wm = w >> 1 >> 1, wn = w & 3;
  const int fr = lane & 15, fs = lane >> 4;

  // ---- panel-affine block mapping ----
  int xb, yb, zb;
  {
    int f0 = blockIdx.x + gridDim.x * (blockIdx.y + gridDim.y * blockIdx.z);
    int g = f0 & 7, s = f0 >> 3;
    if constexpr (MODE == MODE_PROJ) {        // grid (4,32,3)
      xb = s & 3; int p = g + 8 * (s >> 2); yb = p & 31; zb = p >> 5;
    } else if constexpr (MODE == MODE_S) {    // grid (8,8,4)
      xb = s & 7; int p = g + 8 * (s >> 3); yb = p & 7;  zb = p >> 3;
    } else if constexpr (MODE == MODE_FIN) {  // grid (4,16,4)
      xb = s & 3; int p = g + 8 * (s >> 2); yb = p & 15; zb = p >> 4;
    } else {                                  // MODE_BF16: raw
      xb = blockIdx.x; yb = blockIdx.y; zb = blockIdx.z;
    }
  }
  const int z = zb;
  const int mbase = yb * BM, nbase = xb * 256;

  const bf16_t* A  = Abase + (size_t)z * strA;
  const bf16_t* Bt = Bbase + (size_t)z * strB;

  int offA[2][2], offB[2][2];
#pragma unroll
  for (int h = 0; h < 2; h++)
#pragma unroll
    for (int i = 0; i < 2; i++) {
      int c = i * 512 + tid, row = c >> 3;
      int sg = (c & 7) ^ (row & 7);
      if (i < AL) offA[h][i] = (mbase + h * WROWS + row) * lda + sg * 8;
      offB[h][i] = (nbase + h * 128 + row) * ldb + sg * 8;
    }

  const int swz0 = (fs ^ (fr & 7)) * 16;
  const int swz1 = ((4 + fs) ^ (fr & 7)) * 16;

  bf16x8 af[QAF][2], bfv[2][2][2];
  f32x4 acc[MFR][4] = {};

#define STAGE_A(h, kt, bsel) do {                                             \
    char* hb_ = smem + (bsel) * BUFB + (h) * AHB;                             \
    _Pragma("unroll")                                                         \
    for (int i_ = 0; i_ < AL; ++i_)                                           \
      gload_lds16(A + offA[h][i_] + (kt) * 64,                                \
                  (bf16_t*)(hb_ + (i_ * 512 + tid) * 16));                    \
  } while (0)
#define STAGE_B(h, kt, bsel) do {                                             \
    char* hb_ = smem + (bsel) * BUFB + BM * 128 + (h) * 16384;                \
    _Pragma("unroll")                                                         \
    for (int i_ = 0; i_ < BL; ++i_)                                           \
      gload_lds16(Bt + offB[h][i_] + (kt) * 64,                               \
                  (bf16_t*)(hb_ + (i_ * 512 + tid) * 16));                    \
  } while (0)
#define LOAD_A(bsel, mh) do {                                                 \
    const char* ab_ = smem + (bsel) * BUFB + (wm * WROWS) * 128;              \
    _Pragma("unroll")                                                         \
    for (int i_ = 0; i_ < QAF; ++i_) {                                        \
      int rb_ = ((mh) * (WROWS / 2) + i_ * 16 + fr) * 128;                    \
      af[i_][0] = *(const bf16x8*)(ab_ + rb_ + swz0);                         \
      af[i_][1] = *(const bf16x8*)(ab_ + rb_ + swz1);                         \
    }                                                                         \
  } while (0)
#define LOAD_B(bsel, nh) do {                                                 \
    const char* bb_ = smem + (bsel) * BUFB + BM * 128 + (wn * 64) * 128;      \
    _Pragma("unroll")                                                         \
    for (int j_ = 0; j_ < 2; ++j_) {                                          \
      int rb_ = ((nh) * 32 + j_ * 16 + fr) * 128;                             \
      bfv[nh][j_][0] = *(const bf16x8*)(bb_ + rb_ + swz0);                    \
      bfv[nh][j_][1] = *(const bf16x8*)(bb_ + rb_ + swz1);                    \
    }                                                                         \
  } while (0)
#define MFMA_Q(mh, nh) do {                                                   \
    __builtin_amdgcn_s_setprio(1);                                            \
    _Pragma("unroll")                                                         \
    for (int i_ = 0; i_ < QAF; ++i_)                                          \
    _Pragma("unroll")                                                         \
    for (int j_ = 0; j_ < 2; ++j_) {                                          \
      acc[(mh)*QAF + i_][(nh)*2 + j_] = __builtin_amdgcn_mfma_f32_16x16x32_bf16( \
          af[i_][0], bfv[nh][j_][0], acc[(mh)*QAF + i_][(nh)*2 + j_], 0, 0, 0);  \
      acc[(mh)*QAF + i_][(nh)*2 + j_] = __builtin_amdgcn_mfma_f32_16x16x32_bf16( \
          af[i_][1], bfv[nh][j_][1], acc[(mh)*QAF + i_][(nh)*2 + j_], 0, 0, 0);  \
    }                                                                         \
    __builtin_amdgcn_s_setprio(0);                                            \
  } while (0)
#define LGKM0() do { asm volatile("s_waitcnt lgkmcnt(0)" ::: "memory");       \
                     __builtin_amdgcn_sched_barrier(0); } while (0)
#define VMW() do {                                                            \
    if constexpr (AL == 2) asm volatile("s_waitcnt vmcnt(8)" ::: "memory");   \
    else                   asm volatile("s_waitcnt vmcnt(6)" ::: "memory");   \
  } while (0)

  const int NK = K >> 6, NI = NK >> 1;

  STAGE_B(0, 0, 0); STAGE_B(1, 0, 0); STAGE_A(0, 0, 0); STAGE_A(1, 0, 0);
  STAGE_B(0, 1, 1); STAGE_B(1, 1, 1); STAGE_A(0, 1, 1); STAGE_A(1, 1, 1);
  VMW(); BARRIER();

  for (int it = 0; it < NI; ++it) {
    const int ta = (2 * it + 2 < NK) ? 2 * it + 2 : NK - 1;
    const int tb = (2 * it + 3 < NK) ? 2 * it + 3 : NK - 1;
    LOAD_A(0, 0); LOAD_B(0, 0);
    BARRIER(); LGKM0(); MFMA_Q(0, 0); BARRIER();
    LOAD_B(0, 1);
    BARRIER(); LGKM0(); MFMA_Q(0, 1); BARRIER();
    LOAD_A(0, 1);
    STAGE_B(0, ta, 0); STAGE_B(1, ta, 0);
    BARRIER(); LGKM0(); MFMA_Q(1, 1); BARRIER();
    STAGE_A(0, ta, 0); STAGE_A(1, ta, 0);
    VMW();
    BARRIER(); MFMA_Q(1, 0); BARRIER();
    LOAD_A(1, 0); LOAD_B(1, 0);
    BARRIER(); LGKM0(); MFMA_Q(0, 0); BARRIER();
    LOAD_B(1, 1);
    BARRIER(); LGKM0(); MFMA_Q(0, 1); BARRIER();
    LOAD_A(1, 1);
    STAGE_B(0, tb, 1); STAGE_B(1, tb, 1);
    BARRIER(); LGKM0(); MFMA_Q(1, 1); BARRIER();
    STAGE_A(0, tb, 1); STAGE_A(1, tb, 1);
    VMW();
    BARRIER(); MFMA_Q(1, 0); BARRIER();
  }
  asm volatile("s_waitcnt vmcnt(0)" ::: "memory");

  // ---- epilogues ----  C/D frag: col = fr, row = fs*4 + jj
  const int r0 = mbase + wm * WROWS;
  const int c0 = nbase + wn * 64;

  if constexpr (MODE == MODE_PROJ || MODE == MODE_BF16) {
    BARRIER();
    char* ep = smem + w * AHB;
    bf16_t* o = (bf16_t*)outp + (size_t)z * strO;
    const float* bias = nullptr;
    float scale = 1.0f;
    if constexpr (MODE == MODE_PROJ) {
      bias = (z == 0) ? x0 : (z == 1) ? x1 : x2;
      scale = (z == 0) ? 0.03125f : 1.0f;
    }
#pragma unroll
    for (int nf = 0; nf < 4; ++nf) {
      float bv = 0.0f;
      if constexpr (MODE == MODE_PROJ) bv = bias[c0 + nf * 16 + fr];
#pragma unroll
      for (int mf = 0; mf < MFR; ++mf)
#pragma unroll
        for (int jj = 0; jj < 4; ++jj) {
          int row = mf * 16 + fs * 4 + jj;
          int slot = (nf * 2 + (fr >> 3)) ^ ((row >> 1) & 7);
          *(bf16_t*)(ep + row * 128 + slot * 16 + (fr & 7) * 2) =
              f2bf((acc[mf][nf][jj] + bv) * scale);
        }
    }
    const int rl = lane >> 3, sl = lane & 7;
#pragma unroll
    for (int i = 0; i < WROWS / 8; ++i) {
      int row = i * 8 + rl;
      int slot = sl ^ ((row >> 1) & 7);
      uint4 v = *(const uint4*)(ep + row * 128 + slot * 16);
      *(uint4*)&o[(size_t)(r0 + row) * ldo + c0 + sl * 8] = v;
    }
  } else if constexpr (MODE == MODE_S) {
    BARRIER();
    char* ep = smem + w * AHB;
    bf16_t* o = (bf16_t*)outp + (size_t)z * strO;
    // bitmask: 32 u64 words per row (2048 bits); word for this wave's 64 cols
    const unsigned long long* bw =
        (const unsigned long long*)auxp +
        ((size_t)z * L_ + r0) * 32 + (c0 >> 6);
#pragma unroll
    for (int mf = 0; mf < MFR; ++mf) {
#pragma unroll
      for (int jj = 0; jj < 4; ++jj) {
        int row = mf * 16 + fs * 4 + jj;
        unsigned long long wd = bw[(size_t)row * 32];
        float psum = 0.f;
#pragma unroll
        for (int nf = 0; nf < 4; ++nf) {
          int cbit = nf * 16 + fr;
          float e = ((wd >> cbit) & 1ull) ? __expf(acc[mf][nf][jj]) : 0.0f;
          bf16_t eb = f2bf(e);
          psum += bf2f(eb);
          int slot = (nf * 2 + (fr >> 3)) ^ ((row >> 1) & 7);
          *(bf16_t*)(ep + row * 128 + slot * 16 + (fr & 7) * 2) = eb;
        }
#pragma unroll
        for (int off = 8; off; off >>= 1) psum += __shfl_xor(psum, off, 16);
        if (fr == 0)
          rsp[((size_t)z * L_ + r0 + row) * 32 + xb * 4 + wn] = psum;
      }
    }
    const int rl = lane >> 3, sl = lane & 7;
#pragma unroll
    for (int i = 0; i < WROWS / 8; ++i) {
      int row = i * 8 + rl;
      int slot = sl ^ ((row >> 1) & 7);
      uint4 v = *(const uint4*)(ep + row * 128 + slot * 16);
      *(uint4*)&o[(size_t)(r0 + row) * ldo + c0 + sl * 8] = v;
    }
  } else {  // MODE_FIN — fp32 direct
    float* o = (float*)outp + (size_t)z * strO;
    const float* rs = x0 + (size_t)z * L_;
#pragma unroll
    for (int mf = 0; mf < MFR; ++mf) {
#pragma unroll
      for (int jj = 0; jj < 4; ++jj) {
        int r = r0 + mf * 16 + fs * 4 + jj;
        float inv = 1.0f / rs[r];
#pragma unroll
        for (int nf = 0; nf < 4; ++nf) {
          int c = c0 + nf * 16 + fr;
          o[(size_t)r * ldo + c] = acc[mf][nf][jj] * inv + x1[c];
        }
      }
    }
  }
#undef STAGE_A
#undef STAGE_B
#undef LOAD_A
#undef LOAD_B
#undef MFMA_Q
#undef LGKM0
#undef VMW
}

extern "C" void kernel_launch(void* const* d_in, const int* in_sizes, int n_in,
                              void* d_out, int out_size, void* d_ws, size_t ws_size,
                              hipStream_t stream) {
  const float* query = (const float*)d_in[0];
  const float* keyi  = (const float*)d_in[1];
  const float* value = (const float*)d_in[2];
  const int*   mask  = (const int*)d_in[3];
  const float* Wq = (const float*)d_in[4];
  const float* bq = (const float*)d_in[5];
  const float* Wk = (const float*)d_in[6];
  const float* bk = (const float*)d_in[7];
  const float* Wv = (const float*)d_in[8];
  const float* bv = (const float*)d_in[9];
  const float* Wo = (const float*)d_in[10];
  const float* bo = (const float*)d_in[11];

  bf16_t* ws = (bf16_t*)d_ws;
  const size_t NE = (size_t)M_FLAT * D_;  // 8388608
  const size_t WE = (size_t)D_ * D_;      // 1048576
  bf16_t* XQ   = ws;
  bf16_t* XK   = ws + NE;
  bf16_t* XV   = ws + 2 * NE;
  bf16_t* WQT  = ws + 3 * NE;         // WQT,WKT,W2T contiguous (PROJ z-stride)
  bf16_t* WKT  = WQT + WE;
  bf16_t* W2T  = WKT + WE;
  bf16_t* WOT  = W2T + WE;
  bf16_t* WVb  = WOT + WE;
  bf16_t* Qb   = WVb + WE;            // Qb,Kb,VW contiguous (PROJ out z-stride)
  bf16_t* Kb   = Qb + NE;
  bf16_t* VW   = Kb + NE;             // row-major (B*L, D)
  bf16_t* W2tmp= VW + NE;
  float*  rsump= (float*)(W2tmp + WE);              // (B*L)
  float*  c2p  = rsump + (size_t)B_ * L_;           // (1024)
  float*  rspart = c2p + D_;                        // (B*L, 32) partial rowsums
  unsigned long long* bmask =
      (unsigned long long*)(rspart + (size_t)B_ * L_ * 32);  // (B*L*L/64)
  bf16_t* Sb   = ws;                  // S/P (B,L,L) — overlaps XQ+XK (dead after PROJ)
  bf16_t* VWt  = XV;                  // (B) x (D,L) — overlaps XV (dead after PROJ)

  hipFuncSetAttribute((const void*)g8<256, MODE_PROJ>,
                      hipFuncAttributeMaxDynamicSharedMemorySize, 131072);
  hipFuncSetAttribute((const void*)g8<256, MODE_S>,
                      hipFuncAttributeMaxDynamicSharedMemorySize, 131072);
  hipFuncSetAttribute((const void*)g8<128, MODE_BF16>,
                      hipFuncAttributeMaxDynamicSharedMemorySize, 98304);
  hipFuncSetAttribute((const void*)g8<128, MODE_FIN>,
                      hipFuncAttributeMaxDynamicSharedMemorySize, 98304);

  // 0) pack mask to bits (67 MB -> 2 MB, read once)
  pack_mask<<<dim3(65536), dim3(256), 0, stream>>>(mask, bmask);
  // 1) converts
  cvt_bf16<<<dim3(4096), dim3(256), 0, stream>>>(query, XQ);
  cvt_bf16<<<dim3(4096), dim3(256), 0, stream>>>(keyi, XK);
  cvt_bf16<<<dim3(4096), dim3(256), 0, stream>>>(value, XV);
  cvt_bf16<<<dim3(512), dim3(256), 0, stream>>>(Wv, WVb);
  // 2) weight transposes
  transpose_cvt<<<dim3(32, 32), dim3(32, 8), 0, stream>>>(Wq, WQT);
  transpose_cvt<<<dim3(32, 32), dim3(32, 8), 0, stream>>>(Wk, WKT);
  transpose_cvt<<<dim3(32, 32), dim3(32, 8), 0, stream>>>(Wo, WOT);
  // 3) c2 = bv . Wo
  c2_kernel<<<dim3(4), dim3(256), 0, stream>>>(bv, Wo, c2p);
  // 4) W2 = Wv . Wo (bf16), then transpose -> W2T
  g8<128, MODE_BF16><<<dim3(4, 8, 1), 512, 98304, stream>>>(
      WVb, D_, 0, WOT, D_, 0, W2tmp, 0, D_,
      nullptr, nullptr, nullptr, nullptr, nullptr, D_);
  transpose_bf16<<<dim3(32, 32, 1), dim3(32, 8), 0, stream>>>(
      W2tmp, W2T, D_, D_, 0, 0);
  // 5) batched projections (z: 0=Q scaled, 1=K, 2=V.W2 + c2)
  g8<256, MODE_PROJ><<<dim3(4, 32, 3), 512, 131072, stream>>>(
      XQ, D_, (long)NE, WQT, D_, (long)WE, Qb, (long)NE, D_,
      bq, bk, c2p, nullptr, nullptr, D_);
  // 6) VW -> VWt (per batch (L,D) -> (D,L))
  transpose_bf16<<<dim3(32, 64, 4), dim3(32, 8), 0, stream>>>(
      VW, VWt, L_, D_, (long)L_ * D_, (long)D_ * L_);
  // 7) S = Q K^T fused with masked exp -> P (bf16) + partial rowsums
  g8<256, MODE_S><<<dim3(8, 8, 4), 512, 131072, stream>>>(
      Qb, D_, (long)L_ * D_, Kb, D_, (long)L_ * D_, Sb, (long)L_ * L_, L_,
      nullptr, nullptr, nullptr, bmask, rspart, D_);
  // 8) reduce partial rowsums
  reduce_rsum<<<dim3(32), dim3(256), 0, stream>>>(rspart, rsump);
  // 9) out = (P . VWt^T)/rs + bo  -> fp32 d_out
  g8<128, MODE_FIN><<<dim3(4, 16, 4), 512, 98304, stream>>>(
      Sb, L_, (long)L_ * L_, VWt, L_, (long)D_ * L_, d_out, (long)L_ * D_, D_,
      rsump, bo, nullptr, nullptr, nullptr, L_);
}

// Round 7
// 261.970 us; speedup vs baseline: 1.1446x; 1.1446x over previous
//
#include <hip/hip_runtime.h>

#define B_ 4
#define L_ 2048
#define D_ 1024
#define M_FLAT (B_*L_)   // 8192
#define NE_ ((size_t)M_FLAT * D_)   // 8388608
#define WE_ ((size_t)D_ * D_)       // 1048576

typedef unsigned short bf16_t;
typedef __attribute__((ext_vector_type(8))) short bf16x8;
typedef __attribute__((ext_vector_type(4))) float f32x4;

__device__ __forceinline__ bf16_t f2bf(float f) {
  union { float f; unsigned int u; } c; c.f = f;
  unsigned int u = c.u;
  unsigned int r = (u + 0x7fffu + ((u >> 16) & 1u)) >> 16;
  return (bf16_t)r;
}
__device__ __forceinline__ float bf2f(bf16_t h) {
  union { unsigned int u; float f; } c; c.u = ((unsigned int)h) << 16;
  return c.f;
}

__device__ __forceinline__ void gload_lds16(const bf16_t* g, bf16_t* l) {
  __builtin_amdgcn_global_load_lds(
      (const __attribute__((address_space(1))) unsigned int*)g,
      (__attribute__((address_space(3))) unsigned int*)l, 16, 0, 0);
}

#define BARRIER() do { asm volatile("" ::: "memory"); \
                       __builtin_amdgcn_s_barrier();  \
                       asm volatile("" ::: "memory"); } while (0)

// ---- merged fp32 -> bf16 converts: q,k,v -> XQ,XK,XV (contig) + Wv -> WVb ----
__global__ __launch_bounds__(256) void prep_cvt(const float* __restrict__ q,
                                                const float* __restrict__ k,
                                                const float* __restrict__ v,
                                                const float* __restrict__ wv,
                                                bf16_t* __restrict__ xq,
                                                bf16_t* __restrict__ wvb) {
  const float* in; bf16_t* out; size_t li;
  int b = blockIdx.x;
  if (b < 4096)       { in = q;  out = xq;            li = (size_t)b * 256 + threadIdx.x; }
  else if (b < 8192)  { in = k;  out = xq + NE_;      li = (size_t)(b - 4096) * 256 + threadIdx.x; }
  else if (b < 12288) { in = v;  out = xq + 2 * NE_;  li = (size_t)(b - 8192) * 256 + threadIdx.x; }
  else                { in = wv; out = wvb;           li = (size_t)(b - 12288) * 256 + threadIdx.x; }
  const float4* p = (const float4*)in + li * 2;
  float4 a = p[0], bb = p[1];
  union { bf16_t h[8]; uint4 u; } r;
  r.h[0] = f2bf(a.x); r.h[1] = f2bf(a.y); r.h[2] = f2bf(a.z); r.h[3] = f2bf(a.w);
  r.h[4] = f2bf(bb.x); r.h[5] = f2bf(bb.y); r.h[6] = f2bf(bb.z); r.h[7] = f2bf(bb.w);
  ((uint4*)out)[li] = r.u;
}

// ---- 3x fused 1024x1024 fp32 -> transposed bf16 (Wq,Wk,Wo -> WQT,WKT,WOT) ----
__global__ __launch_bounds__(256) void transpose_cvt3(const float* __restrict__ Wq,
                                                      const float* __restrict__ Wk,
                                                      const float* __restrict__ Wo,
                                                      bf16_t* __restrict__ outbase) {
  __shared__ float t[32][33];
  int zz = blockIdx.z;
  const float* Wsrc = (zz == 0) ? Wq : (zz == 1) ? Wk : Wo;
  bf16_t* Wt = outbase + (size_t)(zz == 2 ? 3 : zz) * WE_;  // WQT,WKT,[W2T],WOT
  int c0 = blockIdx.x * 32, r0 = blockIdx.y * 32;
  int tx = threadIdx.x, ty = threadIdx.y;   // block (32,8)
#pragma unroll
  for (int i = 0; i < 4; i++)
    t[ty + i * 8][tx] = Wsrc[(size_t)(r0 + ty + i * 8) * D_ + c0 + tx];
  __syncthreads();
#pragma unroll
  for (int i = 0; i < 4; i++)
    Wt[(size_t)(c0 + ty + i * 8) * D_ + r0 + tx] = f2bf(t[tx][ty + i * 8]);
}

// ---- c2 = bv . Wo  (row vector, 1024) ----
__global__ __launch_bounds__(256) void c2_kernel(const float* __restrict__ bv,
                                                 const float* __restrict__ Wo,
                                                 float* __restrict__ c2) {
  int j = blockIdx.x * 256 + threadIdx.x;  // 1024
  float s = 0.f;
  for (int k = 0; k < D_; k++) s += bv[k] * Wo[(size_t)k * D_ + j];
  c2[j] = s;
}

// ---- pack int32 mask -> 1 bit/elem (64 ints -> one u64 via ballot) ----
__global__ __launch_bounds__(256) void pack_mask(const int* __restrict__ mask,
                                                 unsigned long long* __restrict__ bm) {
  size_t gid = (size_t)blockIdx.x * 256 + threadIdx.x;
  int mi = mask[gid];
  unsigned long long b = __ballot(mi != 0);
  if ((threadIdx.x & 63) == 0) bm[gid >> 6] = b;
}

// ---- reduce 32 rowsum partials -> rsum (guarded) ----
__global__ __launch_bounds__(256) void reduce_rsum(const float* __restrict__ rsp,
                                                   float* __restrict__ rs) {
  int r = blockIdx.x * 256 + threadIdx.x;   // 8192 rows
  float s = 0.f;
#pragma unroll
  for (int j = 0; j < 32; j++) s += rsp[(size_t)r * 32 + j];
  rs[r] = fmaxf(s, 1e-30f);
}

// ================= 8-phase BMx256 BK=64 GEMM =================================
// C = A(MxK) * Bt(NxK)^T.  8 waves (2M x 4N), 512 threads, 2 K-steps/iter.
// LDS swizzle: elem (r,k) at byte r*128 + ((k>>3)^(r&7))*16 + (k&7)*2.
// Staging: exactly 1 half-tile/phase. p0:A0(t1)->b1 p1:A1(t1)->b1
//   p2:B0(t0+2)->b0 p3:B1(t0+2)->b0 [vmcnt(4)] p4:A0(t0+2)->b0 p5:A1(t0+2)->b0
//   p6:B0(t1+2)->b1 p7:B1(t1+2)->b1 [vmcnt(4)].  Tenancy verified: buf A halves
//   die after their LOAD_A phases (p2/p6), B after p1/p5; counted waits cover
//   each consumer 4 phases after issue. Never vmcnt(0) in loop.
#define MODE_PROJ 0  // z=0: Q=(acc+bq)/32; z=1: K=acc+bk; z=2: VW+c2 -> VWt (transposed)
#define MODE_S    1  // P = maskbit ? exp(acc) : 0 (bf16) + partial rowsums
#define MODE_FIN  2  // fp32 out = acc/rs[r] + bias[c]
#define MODE_TR   3  // transposed bf16 out (W2T), no bias

template <int BM, int MODE>
__global__ __launch_bounds__(512, 2)
void g8(const bf16_t* __restrict__ Abase, int lda, long strA,
        const bf16_t* __restrict__ Bbase, int ldb, long strB,
        void* __restrict__ outp, long strO, int ldo,
        const float* __restrict__ x0, const float* __restrict__ x1,
        const float* __restrict__ x2,
        const void* __restrict__ auxp, float* __restrict__ rsp,
        int K) {
  constexpr int WROWS = BM / 2;        // per m-wave rows
  constexpr int QAF   = WROWS / 32;    // frag-rows per A-quadrant
  constexpr int MFR   = WROWS / 16;    // acc rows
  constexpr int AL    = BM / 128;      // gloads per A-half
  constexpr int BL    = 2;             // gloads per B-half
  constexpr int AHB   = WROWS * 128;   // bytes per A-half (= per-wave epi tile)
  constexpr int BUFB  = (BM + 256) * 128;
  extern __shared__ __align__(16) char smem[];

  const int tid = threadIdx.x, lane = tid & 63, w = tid >> 6;
  const int wm = w >> 2, wn = w & 3;
  const int fr = lane & 15, fs = lane >> 4;
  const int z = blockIdx.z;

  // XCD-chunk swizzle over (x,y) plane (r5-proven); z untouched
  int gx = gridDim.x, nxy = gx * gridDim.y;
  int lin = blockIdx.y * gx + blockIdx.x;
  if ((nxy & 7) == 0) { int q = nxy >> 3; lin = (lin & 7) * q + (lin >> 3); }
  const int xb = lin % gx;
  const int mbase = (lin / gx) * BM, nbase = xb * 256;

  const bf16_t* A  = Abase + (size_t)z * strA;
  const bf16_t* Bt = Bbase + (size_t)z * strB;

  int offA[2][2], offB[2][2];
#pragma unroll
  for (int h = 0; h < 2; h++)
#pragma unroll
    for (int i = 0; i < 2; i++) {
      int c = i * 512 + tid, row = c >> 3;
      int sg = (c & 7) ^ (row & 7);
      if (i < AL) offA[h][i] = (mbase + h * WROWS + row) * lda + sg * 8;
      offB[h][i] = (nbase + h * 128 + row) * ldb + sg * 8;
    }

  const int swz0 = (fs ^ (fr & 7)) * 16;
  const int swz1 = ((4 + fs) ^ (fr & 7)) * 16;

  bf16x8 af[QAF][2], bfv[2][2][2];
  f32x4 acc[MFR][4] = {};

#define STAGE_A(h, kt, bsel) do {                                             \
    char* hb_ = smem + (bsel) * BUFB + (h) * AHB;                             \
    _Pragma("unroll")                                                         \
    for (int i_ = 0; i_ < AL; ++i_)                                           \
      gload_lds16(A + offA[h][i_] + (kt) * 64,                                \
                  (bf16_t*)(hb_ + (i_ * 512 + tid) * 16));                    \
  } while (0)
#define STAGE_B(h, kt, bsel) do {                                             \
    char* hb_ = smem + (bsel) * BUFB + BM * 128 + (h) * 16384;                \
    _Pragma("unroll")                                                         \
    for (int i_ = 0; i_ < BL; ++i_)                                           \
      gload_lds16(Bt + offB[h][i_] + (kt) * 64,                               \
                  (bf16_t*)(hb_ + (i_ * 512 + tid) * 16));                    \
  } while (0)
#define LOAD_A(bsel, mh) do {                                                 \
    const char* ab_ = smem + (bsel) * BUFB + (wm * WROWS) * 128;              \
    _Pragma("unroll")                                                         \
    for (int i_ = 0; i_ < QAF; ++i_) {                                        \
      int rb_ = ((mh) * (WROWS / 2) + i_ * 16 + fr) * 128;                    \
      af[i_][0] = *(const bf16x8*)(ab_ + rb_ + swz0);                         \
      af[i_][1] = *(const bf16x8*)(ab_ + rb_ + swz1);                         \
    }                                                                         \
  } while (0)
#define LOAD_B(bsel, nh) do {                                                 \
    const char* bb_ = smem + (bsel) * BUFB + BM * 128 + (wn * 64) * 128;      \
    _Pragma("unroll")                                                         \
    for (int j_ = 0; j_ < 2; ++j_) {                                          \
      int rb_ = ((nh) * 32 + j_ * 16 + fr) * 128;                             \
      bfv[nh][j_][0] = *(const bf16x8*)(bb_ + rb_ + swz0);                    \
      bfv[nh][j_][1] = *(const bf16x8*)(bb_ + rb_ + swz1);                    \
    }                                                                         \
  } while (0)
#define MFMA_Q(mh, nh) do {                                                   \
    __builtin_amdgcn_s_setprio(1);                                            \
    _Pragma("unroll")                                                         \
    for (int i_ = 0; i_ < QAF; ++i_)                                          \
    _Pragma("unroll")                                                         \
    for (int j_ = 0; j_ < 2; ++j_) {                                          \
      acc[(mh)*QAF + i_][(nh)*2 + j_] = __builtin_amdgcn_mfma_f32_16x16x32_bf16( \
          af[i_][0], bfv[nh][j_][0], acc[(mh)*QAF + i_][(nh)*2 + j_], 0, 0, 0);  \
      acc[(mh)*QAF + i_][(nh)*2 + j_] = __builtin_amdgcn_mfma_f32_16x16x32_bf16( \
          af[i_][1], bfv[nh][j_][1], acc[(mh)*QAF + i_][(nh)*2 + j_], 0, 0, 0);  \
    }                                                                         \
    __builtin_amdgcn_s_setprio(0);                                            \
  } while (0)
#define LGKM0() do { asm volatile("s_waitcnt lgkmcnt(0)" ::: "memory");       \
                     __builtin_amdgcn_sched_barrier(0); } while (0)
#define VMW4() asm volatile("s_waitcnt vmcnt(4)" ::: "memory")

  const int NK = K >> 6, NI = NK >> 1;

  // prologue: t0 fully -> buf0; B halves of t1 -> buf1 (A(t1) staged at p0/p1)
  STAGE_B(0, 0, 0); STAGE_B(1, 0, 0); STAGE_A(0, 0, 0); STAGE_A(1, 0, 0);
  STAGE_B(0, 1, 1); STAGE_B(1, 1, 1);
  VMW4(); BARRIER();

  for (int it = 0; it < NI; ++it) {
    const int t1 = 2 * it + 1;
    const int ta = (2 * it + 2 < NK) ? 2 * it + 2 : NK - 1;
    const int tb = (2 * it + 3 < NK) ? 2 * it + 3 : NK - 1;
    // p0
    LOAD_A(0, 0); LOAD_B(0, 0);
    STAGE_A(0, t1, 1);
    BARRIER(); LGKM0(); MFMA_Q(0, 0); BARRIER();
    // p1
    LOAD_B(0, 1);
    STAGE_A(1, t1, 1);
    BARRIER(); LGKM0(); MFMA_Q(0, 1); BARRIER();
    // p2
    LOAD_A(0, 1);
    STAGE_B(0, ta, 0);
    BARRIER(); LGKM0(); MFMA_Q(1, 1); BARRIER();
    // p3
    STAGE_B(1, ta, 0);
    VMW4();                      // A(t1) landed before p4 reads buf1
    BARRIER(); MFMA_Q(1, 0); BARRIER();
    // p4
    LOAD_A(1, 0); LOAD_B(1, 0);
    STAGE_A(0, ta, 0);
    BARRIER(); LGKM0(); MFMA_Q(0, 0); BARRIER();
    // p5
    LOAD_B(1, 1);
    STAGE_A(1, ta, 0);
    BARRIER(); LGKM0(); MFMA_Q(0, 1); BARRIER();
    // p6
    LOAD_A(1, 1);
    STAGE_B(0, tb, 1);
    BARRIER(); LGKM0(); MFMA_Q(1, 1); BARRIER();
    // p7
    STAGE_B(1, tb, 1);
    VMW4();                      // ta fully landed before next-iter p0 reads buf0
    BARRIER(); MFMA_Q(1, 0); BARRIER();
  }
  asm volatile("s_waitcnt vmcnt(0)" ::: "memory");

  // ---- epilogues ----  C/D frag: col = fr, row = fs*4 + jj
  const int r0 = mbase + wm * WROWS;
  const int c0 = nbase + wn * 64;

  if constexpr (MODE == MODE_PROJ) {
    BARRIER();
    char* ep = smem + w * AHB;
    if (z < 2) {   // row-major bf16 with bias+scale, coalesced via LDS restage
      bf16_t* o = (bf16_t*)outp + (size_t)z * strO;
      const float* bias = (z == 0) ? x0 : x1;
      const float scale = (z == 0) ? 0.03125f : 1.0f;
#pragma unroll
      for (int nf = 0; nf < 4; ++nf) {
        float bv = bias[c0 + nf * 16 + fr];
#pragma unroll
        for (int mf = 0; mf < MFR; ++mf)
#pragma unroll
          for (int jj = 0; jj < 4; ++jj) {
            int row = mf * 16 + fs * 4 + jj;
            int slot = (nf * 2 + (fr >> 3)) ^ ((row >> 1) & 7);
            *(bf16_t*)(ep + row * 128 + slot * 16 + (fr & 7) * 2) =
                f2bf((acc[mf][nf][jj] + bv) * scale);
          }
      }
      asm volatile("s_waitcnt lgkmcnt(0)" ::: "memory");
      const int rl = lane >> 3, sl = lane & 7;
#pragma unroll
      for (int i = 0; i < WROWS / 8; ++i) {
        int row = i * 8 + rl;
        int slot = sl ^ ((row >> 1) & 7);
        uint4 vv = *(const uint4*)(ep + row * 128 + slot * 16);
        *(uint4*)&o[(size_t)(r0 + row) * ldo + c0 + sl * 8] = vv;
      }
    } else {   // z==2: VW + c2 -> VWt[b][c][r] transposed, coalesced
      bf16_t* ob = (bf16_t*)auxp;
      const int bidx = r0 >> 11, rb = r0 & (L_ - 1);
      ob += (size_t)bidx * D_ * L_;
#pragma unroll
      for (int nf = 0; nf < 4; ++nf) {
        int coll = nf * 16 + fr;
        float bv = x2[c0 + coll];
        int xm = (coll & (WROWS / 8 - 1)) << 3;
#pragma unroll
        for (int mf = 0; mf < MFR; ++mf) {
          int rbase = mf * 16 + fs * 4;
          union { bf16_t h[4]; uint2 u; } pk;
#pragma unroll
          for (int jj = 0; jj < 4; ++jj) pk.h[jj] = f2bf(acc[mf][nf][jj] + bv);
          *(uint2*)(ep + coll * (WROWS * 2) + 2 * (rbase ^ xm)) = pk.u;
        }
      }
      asm volatile("s_waitcnt lgkmcnt(0)" ::: "memory");
      constexpr int LPC = WROWS / 8;
      constexpr int CPI = 64 / LPC;
      const int colr = lane / LPC;
      const int rc = (lane % LPC) * 8;
#pragma unroll
      for (int i2 = 0; i2 < LPC; ++i2) {
        int coll = i2 * CPI + colr;
        int xm = (coll & (WROWS / 8 - 1)) << 3;
        uint4 vv = *(const uint4*)(ep + coll * (WROWS * 2) + 2 * (rc ^ xm));
        *(uint4*)&ob[(size_t)(c0 + coll) * L_ + rb + rc] = vv;
      }
    }
  } else if constexpr (MODE == MODE_TR) {   // W2T: transposed, no bias
    BARRIER();
    char* ep = smem + w * AHB;
    bf16_t* ob = (bf16_t*)outp;
#pragma unroll
    for (int nf = 0; nf < 4; ++nf) {
      int coll = nf * 16 + fr;
      int xm = (coll & (WROWS / 8 - 1)) << 3;
#pragma unroll
      for (int mf = 0; mf < MFR; ++mf) {
        int rbase = mf * 16 + fs * 4;
        union { bf16_t h[4]; uint2 u; } pk;
#pragma unroll
        for (int jj = 0; jj < 4; ++jj) pk.h[jj] = f2bf(acc[mf][nf][jj]);
        *(uint2*)(ep + coll * (WROWS * 2) + 2 * (rbase ^ xm)) = pk.u;
      }
    }
    asm volatile("s_waitcnt lgkmcnt(0)" ::: "memory");
    constexpr int LPC = WROWS / 8;
    constexpr int CPI = 64 / LPC;
    const int colr = lane / LPC;
    const int rc = (lane % LPC) * 8;
#pragma unroll
    for (int i2 = 0; i2 < LPC; ++i2) {
      int coll = i2 * CPI + colr;
      int xm = (coll & (WROWS / 8 - 1)) << 3;
      uint4 vv = *(const uint4*)(ep + coll * (WROWS * 2) + 2 * (rc ^ xm));
      *(uint4*)&ob[(size_t)(c0 + coll) * ldo + r0 + rc] = vv;
    }
  } else if constexpr (MODE == MODE_S) {
    BARRIER();
    char* ep = smem + w * AHB;
    bf16_t* o = (bf16_t*)outp + (size_t)z * strO;
    const unsigned long long* bw =
        (const unsigned long long*)auxp +
        ((size_t)z * L_ + r0) * 32 + (c0 >> 6);
#pragma unroll
    for (int mf = 0; mf < MFR; ++mf) {
#pragma unroll
      for (int jj = 0; jj < 4; ++jj) {
        int row = mf * 16 + fs * 4 + jj;
        unsigned long long wd = bw[(size_t)row * 32];
        float psum = 0.f;
#pragma unroll
        for (int nf = 0; nf < 4; ++nf) {
          int cbit = nf * 16 + fr;
          float e = ((wd >> cbit) & 1ull) ? __expf(acc[mf][nf][jj]) : 0.0f;
          bf16_t eb = f2bf(e);
          psum += bf2f(eb);
          int slot = (nf * 2 + (fr >> 3)) ^ ((row >> 1) & 7);
          *(bf16_t*)(ep + row * 128 + slot * 16 + (fr & 7) * 2) = eb;
        }
#pragma unroll
        for (int off = 8; off; off >>= 1) psum += __shfl_xor(psum, off, 16);
        if (fr == 0)
          rsp[((size_t)z * L_ + r0 + row) * 32 + xb * 4 + wn] = psum;
      }
    }
    asm volatile("s_waitcnt lgkmcnt(0)" ::: "memory");
    const int rl = lane >> 3, sl = lane & 7;
#pragma unroll
    for (int i = 0; i < WROWS / 8; ++i) {
      int row = i * 8 + rl;
      int slot = sl ^ ((row >> 1) & 7);
      uint4 vv = *(const uint4*)(ep + row * 128 + slot * 16);
      *(uint4*)&o[(size_t)(r0 + row) * ldo + c0 + sl * 8] = vv;
    }
  } else {  // MODE_FIN — fp32 direct
    float* o = (float*)outp + (size_t)z * strO;
    const float* rs = x0 + (size_t)z * L_;
#pragma unroll
    for (int mf = 0; mf < MFR; ++mf) {
#pragma unroll
      for (int jj = 0; jj < 4; ++jj) {
        int r = r0 + mf * 16 + fs * 4 + jj;
        float inv = 1.0f / rs[r];
#pragma unroll
        for (int nf = 0; nf < 4; ++nf) {
          int c = c0 + nf * 16 + fr;
          o[(size_t)r * ldo + c] = acc[mf][nf][jj] * inv + x1[c];
        }
      }
    }
  }
#undef STAGE_A
#undef STAGE_B
#undef LOAD_A
#undef LOAD_B
#undef MFMA_Q
#undef LGKM0
#undef VMW4
}

extern "C" void kernel_launch(void* const* d_in, const int* in_sizes, int n_in,
                              void* d_out, int out_size, void* d_ws, size_t ws_size,
                              hipStream_t stream) {
  const float* query = (const float*)d_in[0];
  const float* keyi  = (const float*)d_in[1];
  const float* value = (const float*)d_in[2];
  const int*   mask  = (const int*)d_in[3];
  const float* Wq = (const float*)d_in[4];
  const float* bq = (const float*)d_in[5];
  const float* Wk = (const float*)d_in[6];
  const float* bk = (const float*)d_in[7];
  const float* Wv = (const float*)d_in[8];
  const float* bv = (const float*)d_in[9];
  const float* Wo = (const float*)d_in[10];
  const float* bo = (const float*)d_in[11];

  bf16_t* ws = (bf16_t*)d_ws;
  bf16_t* XQ   = ws;                  // XQ,XK,XV contiguous (PROJ A z-stride)
  bf16_t* XK   = ws + NE_;
  bf16_t* XV   = ws + 2 * NE_;
  bf16_t* WQT  = ws + 3 * NE_;        // WQT,WKT,W2T contiguous (PROJ B z-stride)
  bf16_t* WKT  = WQT + WE_;
  bf16_t* W2T  = WKT + WE_;
  bf16_t* WOT  = W2T + WE_;
  bf16_t* WVb  = WOT + WE_;
  bf16_t* Qb   = WVb + WE_;           // Qb,Kb contiguous (PROJ out z-stride)
  bf16_t* Kb   = Qb + NE_;
  bf16_t* VWt  = Kb + NE_;            // (B) x (D, L), written by PROJ z=2
  float*  rsump= (float*)(VWt + NE_);               // (B*L)
  float*  c2p  = rsump + (size_t)B_ * L_;           // (1024)
  float*  rspart = c2p + D_;                        // (B*L, 32)
  unsigned long long* bmask =
      (unsigned long long*)(rspart + (size_t)B_ * L_ * 32);  // (B*L*L/64)
  bf16_t* Sb   = ws;                  // S/P (B,L,L) overlaps XQ+XK+XV-head (dead after PROJ)

  hipFuncSetAttribute((const void*)g8<256, MODE_PROJ>,
                      hipFuncAttributeMaxDynamicSharedMemorySize, 131072);
  hipFuncSetAttribute((const void*)g8<256, MODE_S>,
                      hipFuncAttributeMaxDynamicSharedMemorySize, 131072);
  hipFuncSetAttribute((const void*)g8<128, MODE_TR>,
                      hipFuncAttributeMaxDynamicSharedMemorySize, 98304);
  hipFuncSetAttribute((const void*)g8<128, MODE_FIN>,
                      hipFuncAttributeMaxDynamicSharedMemorySize, 98304);

  // 1) merged converts + mask pack + weight transposes + c2
  prep_cvt<<<dim3(12800), dim3(256), 0, stream>>>(query, keyi, value, Wv, XQ, WVb);
  pack_mask<<<dim3(65536), dim3(256), 0, stream>>>(mask, bmask);
  transpose_cvt3<<<dim3(32, 32, 3), dim3(32, 8), 0, stream>>>(Wq, Wk, Wo, WQT);
  c2_kernel<<<dim3(4), dim3(256), 0, stream>>>(bv, Wo, c2p);
  // 2) W2T = (Wv.Wo)^T directly (transposed epilogue)
  g8<128, MODE_TR><<<dim3(4, 8, 1), 512, 98304, stream>>>(
      WVb, D_, 0, WOT, D_, 0, W2T, 0, D_,
      nullptr, nullptr, nullptr, nullptr, nullptr, D_);
  // 3) batched projections (z: 0=Q scaled, 1=K; 2=V.W2+c2 -> VWt transposed)
  g8<256, MODE_PROJ><<<dim3(4, 32, 3), 512, 131072, stream>>>(
      XQ, D_, (long)NE_, WQT, D_, (long)WE_, Qb, (long)NE_, D_,
      bq, bk, c2p, VWt, nullptr, D_);
  // 4) S = Q K^T fused with masked exp -> P (bf16) + partial rowsums
  g8<256, MODE_S><<<dim3(8, 8, 4), 512, 131072, stream>>>(
      Qb, D_, (long)L_ * D_, Kb, D_, (long)L_ * D_, Sb, (long)L_ * L_, L_,
      nullptr, nullptr, nullptr, bmask, rspart, D_);
  // 5) reduce partial rowsums
  reduce_rsum<<<dim3(32), dim3(256), 0, stream>>>(rspart, rsump);
  // 6) out = (P . VWt^T)/rs + bo  -> fp32 d_out
  g8<128, MODE_FIN><<<dim3(4, 16, 4), 512, 98304, stream>>>(
      Sb, L_, (long)L_ * L_, VWt, L_, (long)D_ * L_, d_out, (long)L_ * D_, D_,
      rsump, bo, nullptr, nullptr, nullptr, L_);
}